// Round 8
// baseline (1506.013 us; speedup 1.0000x reference)
//
#include <hip/hip_runtime.h>
#include <hip/hip_bf16.h>
#include <cstdint>

#define NB 8192
#define TSTEPS 48

typedef __hip_bfloat16 bf16;
typedef short bf16x8 __attribute__((ext_vector_type(8)));
typedef float f32x4 __attribute__((ext_vector_type(4)));

__device__ __forceinline__ float sigf(float x) { return 1.0f / (1.0f + __expf(-x)); }
__device__ __forceinline__ float tanhf_fast(float x) { return 2.0f / (1.0f + __expf(-2.0f * x)) - 1.0f; }

// CK-style async global->LDS, 16B per lane. LDS dest = wave-uniform base + lane*16.
__device__ __forceinline__ void gld_lds16(const void* g, void* l) {
  typedef const __attribute__((address_space(1))) unsigned int* gp_t;
  typedef __attribute__((address_space(3))) unsigned int* lp_t;
  __builtin_amdgcn_global_load_lds(reinterpret_cast<gp_t>(reinterpret_cast<uintptr_t>(g)),
                                   reinterpret_cast<lp_t>(reinterpret_cast<uintptr_t>(l)),
                                   16, 0, 0);
}

// ---------------- feats precompute: [T, N, 32] bf16, upper 16 cols zero ----------------
__global__ void feats_kernel(const float* __restrict__ x, const float* __restrict__ coords,
                             const float* __restrict__ env, const float* __restrict__ areas,
                             const float* __restrict__ bird, bf16* __restrict__ feats) {
  int idx = blockIdx.x * 256 + threadIdx.x;  // = t*NB + n
  int n = idx & (NB - 1);
  int t = idx >> 13;
  __align__(16) bf16 v[32];
  v[0] = __float2bfloat16(x[n * TSTEPS + t]);
  v[1] = __float2bfloat16(coords[n * 2 + 0]);
  v[2] = __float2bfloat16(coords[n * 2 + 1]);
#pragma unroll
  for (int e = 0; e < 10; ++e) v[3 + e] = __float2bfloat16(env[(n * 10 + e) * TSTEPS + t]);
  v[13] = __float2bfloat16(areas[n]);
  v[14] = __float2bfloat16(bird[(n * 2 + 0) * TSTEPS + t]);
  v[15] = __float2bfloat16(bird[(n * 2 + 1) * TSTEPS + t]);
#pragma unroll
  for (int f = 16; f < 32; ++f) v[f] = __float2bfloat16(0.0f);
  bf16* dst = feats + (size_t)idx * 32;
#pragma unroll
  for (int c = 0; c < 4; ++c) ((bf16x8*)dst)[c] = ((const bf16x8*)v)[c];
}

// ---------------- weight packing ----------------
// packed gate-column order: j' = 128*q + 32*g + s  <->  original row j = 256*g + 32*q + s
__device__ __forceinline__ int orig_row(int jp) {
  int q = jp >> 7, g = (jp >> 5) & 3, s = jp & 31;
  return g * 256 + q * 32 + s;
}

// WA: [1024, 288] = [W_hh0 (256) | Wc0 = W_ih0@W_in (16) | zeros (16)]
__global__ void packA_kernel(const float* __restrict__ W_hh0, const float* __restrict__ W_ih0,
                             const float* __restrict__ W_in, bf16* __restrict__ WA) {
  int idx = blockIdx.x * 256 + threadIdx.x;  // < 1024*288
  int jp = idx / 288, col = idx % 288;
  int j = orig_row(jp);
  float val = 0.0f;
  if (col < 256) {
    val = W_hh0[j * 256 + col];
  } else if (col < 272) {
    int f = col - 256;
    float s = 0.0f;
    for (int k = 0; k < 256; ++k) s += W_ih0[j * 256 + k] * W_in[k * 16 + f];
    val = s;
  }
  WA[(size_t)jp * 288 + col] = __float2bfloat16(val);
}

// WB: [1024, 512] = [W_ih1 (256) | W_hh1 (256)]
__global__ void packB_kernel(const float* __restrict__ W_ih1, const float* __restrict__ W_hh1,
                             bf16* __restrict__ WB) {
  int idx = blockIdx.x * 256 + threadIdx.x;  // < 1024*512
  int jp = idx >> 9, col = idx & 511;
  int j = orig_row(jp);
  float val = (col < 256) ? W_ih1[j * 256 + col] : W_hh1[j * 256 + (col - 256)];
  WB[(size_t)jp * 512 + col] = __float2bfloat16(val);
}

__global__ void packBias_kernel(const float* __restrict__ b_ih, const float* __restrict__ b_hh,
                                float* __restrict__ bA, float* __restrict__ bB) {
  int idx = blockIdx.x * 256 + threadIdx.x;  // < 2048
  int layer = idx >> 10, jp = idx & 1023;
  int j = orig_row(jp);
  float v = b_ih[layer * 1024 + j] + b_hh[layer * 1024 + j];
  if (layer == 0) bA[jp] = v; else bB[jp] = v;
}

// ---------------- fused GEMM + LSTM cell step, combined A/B phases ----------------
// phase = blockIdx.z + phase0:  0 = layer-1 at tB (B), 1 = layer-0 at tA (A).
// R8: BK=64 (was 32). R7's result falsified the bytes-model (16 MB/step cut bought
// only 1.2 us/step); the cost is the COUNT of barrier vmcnt-drains (latency convoy),
// ~1 us each. BK=64 halves them: phase B 16->8 iters, phase A 4 BK64 + 1 BK32 tail
// (feats). Staging 32 KB aliased in Gs (33.8 KB) -> occupancy still 4 blocks/CU.
__global__ __launch_bounds__(256, 4) void lstm_step(
    const bf16* __restrict__ h0r, bf16* __restrict__ h0w,
    const bf16* __restrict__ h1r, bf16* __restrict__ h1w,
    const bf16* __restrict__ feats,
    const bf16* __restrict__ WA, const bf16* __restrict__ WB,
    const float* __restrict__ bA, const float* __restrict__ bB,
    bf16* __restrict__ c0, bf16* __restrict__ c1,
    float* __restrict__ out, int tA, int tB, int phase0, int lastA, int lastB) {
  __shared__ float Gs[64 * 132];     // 33.8 KB; staging aliases the front 32 KB
  bf16* As = (bf16*)Gs;              // BK64: [128][64]; tail: [128][32]
  bf16* Bs = As + 128 * 64;          // BK64: [128][64]; tail: [128][32]

  const int tid = threadIdx.x;
  const int wid = tid >> 6, lane = tid & 63;
  const int quad = lane >> 4, l16 = lane & 15;
  const int mb = (wid >> 1) * 64, nb = (wid & 1) * 64;
  const int rowbase = blockIdx.x * 128;
  const int q = blockIdx.y;
  const int isA = blockIdx.z + phase0;  // 0 = B, 1 = A

  const bf16* Wp = isA ? WA : WB;
  const int KW = isA ? 288 : 512;
  const int K64 = isA ? 4 : 8;
  const int t = isA ? tA : tB;

  f32x4 acc[4][4];
#pragma unroll
  for (int i = 0; i < 4; ++i)
#pragma unroll
    for (int j = 0; j < 4; ++j) acc[i][j] = f32x4{0.f, 0.f, 0.f, 0.f};

  // BK64 staging map: wave w stages rows w*32..w*32+31 of both tiles.
  // Instr p covers rows w*32+p*8+(lane>>3), chunk (lane&7)*8 elems (128B/row).
  const int srow8 = lane >> 3;         // 0..7
  const int sch8 = (lane & 7) * 8;     // source chunk (elems)
  const int arow = wid * 32 + srow8;   // + p*8 per instr
  bf16* lA = As + wid * 2048;          // wave block: 32 rows x 64 cols
  bf16* lB = Bs + wid * 2048;
  const bf16* Wqbase = Wp + (size_t)(q * 128) * KW;

  for (int kb = 0; kb < K64; ++kb) {
    const bf16* Asrc = ((!isA || kb < 4) ? ((!isA && kb >= 4) ? (h1r + (kb - 4) * 64)
                                                              : (h0r + kb * 64))
                                         : h0r) +
                       (size_t)rowbase * 256;
    const bf16* Bsrc = Wqbase + kb * 64;
#pragma unroll
    for (int p = 0; p < 4; ++p) {
      int r = arow + p * 8;
      gld_lds16(Asrc + (size_t)r * 256 + sch8, lA + p * 512);
      gld_lds16(Bsrc + (size_t)r * KW + sch8, lB + p * 512);
    }
    __syncthreads();  // vmcnt drain publishes staged tiles (m97-verified structure)
#pragma unroll
    for (int k2 = 0; k2 < 2; ++k2) {
      bf16x8 af[4], bfr[4];
#pragma unroll
      for (int i = 0; i < 4; ++i)
        af[i] = *(const bf16x8*)&As[(mb + i * 16 + l16) * 64 + k2 * 32 + quad * 8];
#pragma unroll
      for (int j = 0; j < 4; ++j)
        bfr[j] = *(const bf16x8*)&Bs[(nb + j * 16 + l16) * 64 + k2 * 32 + quad * 8];
#pragma unroll
      for (int i = 0; i < 4; ++i)
#pragma unroll
        for (int j = 0; j < 4; ++j)
          acc[i][j] = __builtin_amdgcn_mfma_f32_16x16x32_bf16(af[i], bfr[j], acc[i][j], 0, 0, 0);
    }
    __syncthreads();  // retire reads before next staging writes
  }

  if (isA) {
    // BK32 tail: A = feats[t] (128x32), B = WA cols 256..287 (128x32)
    const int arow32 = wid * 32 + (lane >> 2);  // rows +0 / +16 over two instrs
    const int sch4 = (lane & 3) * 8;
    bf16* lA32 = As + wid * 1024;  // [128][32] layout
    bf16* lB32 = Bs + wid * 1024;
    const bf16* Af = feats + ((size_t)t * NB + rowbase + arow32) * 32 + sch4;
    const bf16* Bf = Wqbase + (size_t)arow32 * 288 + 256 + sch4;
    gld_lds16(Af, lA32);
    gld_lds16(Af + (size_t)16 * 32, lA32 + 512);
    gld_lds16(Bf, lB32);
    gld_lds16(Bf + (size_t)16 * 288, lB32 + 512);
    __syncthreads();
    bf16x8 af[4], bfr[4];
#pragma unroll
    for (int i = 0; i < 4; ++i) af[i] = *(const bf16x8*)&As[(mb + i * 16 + l16) * 32 + quad * 8];
#pragma unroll
    for (int j = 0; j < 4; ++j) bfr[j] = *(const bf16x8*)&Bs[(nb + j * 16 + l16) * 32 + quad * 8];
#pragma unroll
    for (int i = 0; i < 4; ++i)
#pragma unroll
      for (int j = 0; j < 4; ++j)
        acc[i][j] = __builtin_amdgcn_mfma_f32_16x16x32_bf16(af[i], bfr[j], acc[i][j], 0, 0, 0);
    __syncthreads();
  }

  // epilogue: half-block at a time through LDS (aliases As/Bs; all waves past final barrier)
  const float* bias = isA ? bA : bB;
  bf16* cst = isA ? c0 : c1;
  bf16* hout = isA ? h0w : h1w;
  const int last = isA ? lastA : lastB;
  float* out_h = out + (size_t)(isA ? 0 : 1) * NB * 256;
  float* out_c = out + (size_t)(isA ? 2 : 3) * NB * 256;

  const int s = tid & 31;
  const int rg = tid >> 5;  // 0..7
  const float bi = bias[q * 128 + 0 + s];
  const float bf_ = bias[q * 128 + 32 + s];
  const float bg = bias[q * 128 + 64 + s];
  const float bo = bias[q * 128 + 96 + s];
  const int u = q * 32 + s;

  for (int half = 0; half < 2; ++half) {
    if ((wid >> 1) == half) {
#pragma unroll
      for (int i = 0; i < 4; ++i)
#pragma unroll
        for (int j = 0; j < 4; ++j)
#pragma unroll
          for (int r = 0; r < 4; ++r)
            Gs[(i * 16 + quad * 4 + r) * 132 + nb + j * 16 + l16] = acc[i][j][r];
    }
    __syncthreads();
#pragma unroll
    for (int it = 0; it < 8; ++it) {
      int rl = rg * 8 + it;  // 0..63
      int n = rowbase + half * 64 + rl;
      float gi = sigf(Gs[rl * 132 + 0 + s] + bi);
      float gf = sigf(Gs[rl * 132 + 32 + s] + bf_);
      float gg = tanhf_fast(Gs[rl * 132 + 64 + s] + bg);
      float go = sigf(Gs[rl * 132 + 96 + s] + bo);
      size_t ci = (size_t)n * 256 + u;
      float c = __bfloat162float(cst[ci]);
      float cn = gf * c + gi * gg;
      float hn = go * tanhf_fast(cn);
      if (!last) cst[ci] = __float2bfloat16(cn);  // carry (bf16); dead at final step
      hout[ci] = __float2bfloat16(hn);
      if (last) {
        out_h[ci] = hn;
        out_c[ci] = cn;  // f32 output keeps full accumulator precision
      }
    }
    __syncthreads();
  }
}

extern "C" void kernel_launch(void* const* d_in, const int* in_sizes, int n_in,
                              void* d_out, int out_size, void* d_ws, size_t ws_size,
                              hipStream_t stream) {
  const float* x = (const float*)d_in[0];
  const float* coords = (const float*)d_in[1];
  const float* env = (const float*)d_in[2];
  const float* areas = (const float*)d_in[3];
  const float* bird = (const float*)d_in[4];
  const float* W_in = (const float*)d_in[5];
  const float* W_ih = (const float*)d_in[6];  // [2,1024,256]
  const float* W_hh = (const float*)d_in[7];  // [2,1024,256]
  const float* b_ih = (const float*)d_in[8];  // [2,1024]
  const float* b_hh = (const float*)d_in[9];  // [2,1024]
  float* out = (float*)d_out;

  const size_t MB = 1 << 20;
  char* w0 = (char*)d_ws;
  // layout: [H0_0 4][H1_0 4][H0_1 4][H1_1 4][c0 4][c1 4][feats 24][WA][WB][bA][bB] (MB)
  auto H0 = [&](int i) { return (bf16*)(w0 + (size_t)i * 8 * MB); };
  auto H1 = [&](int i) { return (bf16*)(w0 + 4 * MB + (size_t)i * 8 * MB); };
  bf16* c0 = (bf16*)(w0 + 16 * MB);
  bf16* c1 = (bf16*)(w0 + 20 * MB);
  bf16* feats = (bf16*)(w0 + 24 * MB);
  bf16* WA = (bf16*)(w0 + 48 * MB);
  bf16* WB = (bf16*)(w0 + 49 * MB);
  float* bA = (float*)(w0 + 50 * MB);
  float* bB = (float*)(w0 + 50 * MB + 4096);

  // zero H0[1], H1[1] (initial state) and c0, c1 — contiguous [8MB, 24MB)
  hipMemsetAsync(w0 + 8 * MB, 0, 16 * MB, stream);

  feats_kernel<<<(NB * TSTEPS) / 256, 256, 0, stream>>>(x, coords, env, areas, bird, feats);
  packA_kernel<<<(1024 * 288) / 256, 256, 0, stream>>>(W_hh, W_ih, W_in, WA);
  packB_kernel<<<(1024 * 512) / 256, 256, 0, stream>>>(W_ih + 1024 * 256, W_hh + 1024 * 256, WB);
  packBias_kernel<<<2048 / 256, 256, 0, stream>>>(b_ih, b_hh, bA, bB);

  // A(0): reads H0[1] (zero), writes H0[0]
  lstm_step<<<dim3(64, 8, 1), 256, 0, stream>>>(
      H0(1), H0(0), H1(0), H1(1), feats, WA, WB, bA, bB, c0, c1, out,
      /*tA*/0, /*tB*/0, /*phase0*/1, /*lastA*/0, /*lastB*/0);
  // combined: z=0 -> B(s), z=1 -> A(s+1). Both read h0(s)=H0[s&1].
  for (int s2 = 0; s2 <= 46; ++s2) {
    int pa = (s2 + 1) & 1, pb = s2 & 1;
    lstm_step<<<dim3(64, 8, 2), 256, 0, stream>>>(
        H0(pb), H0(pa), H1(pa), H1(pb), feats, WA, WB, bA, bB, c0, c1, out,
        /*tA*/s2 + 1, /*tB*/s2, /*phase0*/0, /*lastA*/(s2 == 46), /*lastB*/0);
  }
  // B(47): reads H0[1], H1[0]; writes H1[1]
  lstm_step<<<dim3(64, 8, 1), 256, 0, stream>>>(
      H0(1), H0(0), H1(0), H1(1), feats, WA, WB, bA, bB, c0, c1, out,
      /*tA*/0, /*tB*/47, /*phase0*/0, /*lastA*/0, /*lastB*/1);
}